// Round 1
// baseline (645.037 us; speedup 1.0000x reference)
//
#include <hip/hip_runtime.h>
#include <math.h>

#define HW 9216          // 96*96
#define WID 96
#define CIN 256
#define COUT 256

// ws layout (floats):
//   off   : [0, 331776)        B*18*HW
//   w_t   : [331776, 921600)   9*256*256, w_t[(k*256+c)*256+oc] = conv_w[oc][c][k]
//   stats : [921600, 921728)   64 * (mean, rsig)

__global__ __launch_bounds__(256) void init_off(float* __restrict__ off,
                                                const float* __restrict__ offset_b) {
    int i = blockIdx.x * 256 + threadIdx.x;
    if (i < 331776) {
        int ch = (i / HW) % 18;
        off[i] = offset_b[ch];
    }
}

__global__ __launch_bounds__(256) void transpose_w(const float* __restrict__ cw,
                                                   float* __restrict__ wt) {
    int i = blockIdx.x * 256 + threadIdx.x;   // [0, 589824)
    if (i >= 589824) return;
    int oc = i & 255;
    int c  = (i >> 8) & 255;
    int k  = i >> 16;                         // 256*256 = 65536
    wt[i] = cw[(oc * CIN + c) * 9 + k];
}

// 3x3 pad-1 conv producing the 18 offset channels. Grid: 8 c-chunks * 72 = 576 blocks.
__global__ __launch_bounds__(256) void offset_conv(const float* __restrict__ x,
                                                   const float* __restrict__ ow,
                                                   float* __restrict__ off) {
    int chunk = blockIdx.x / 72;                       // uniform per block
    int pg = (blockIdx.x % 72) * 256 + threadIdx.x;    // [0, 18432)
    int b  = pg / HW;
    int p  = pg % HW;
    int ho = p / WID, wo = p % WID;
    const float* xb = x + (size_t)b * CIN * HW;

    float acc[18];
#pragma unroll
    for (int ch = 0; ch < 18; ch++) acc[ch] = 0.f;

    int c0 = chunk * 32;
    for (int ci = 0; ci < 32; ci++) {
        int c = c0 + ci;
        const float* xc = xb + (size_t)c * HW;
#pragma unroll
        for (int ky = 0; ky < 3; ky++) {
            int y = ho - 1 + ky;
            if (y < 0 || y >= 96) continue;
#pragma unroll
            for (int kx = 0; kx < 3; kx++) {
                int xx = wo - 1 + kx;
                float xv = (xx >= 0 && xx < 96) ? xc[y * WID + xx] : 0.f;
                int widx = c * 9 + ky * 3 + kx;        // uniform -> s_load
#pragma unroll
                for (int ch = 0; ch < 18; ch++)
                    acc[ch] += xv * ow[ch * (CIN * 9) + widx];
            }
        }
    }
#pragma unroll
    for (int ch = 0; ch < 18; ch++)
        atomicAdd(&off[((size_t)b * 18 + ch) * HW + p], acc[ch]);
}

// Main deformable conv. Block tile: 256 oc x 32 positions; thread: 4 oc x 8 pos.
// Grid: B * Ho * 3 = 576 blocks.
__global__ __launch_bounds__(256) void dconv_main(const float* __restrict__ x,
                                                  const float* __restrict__ off,
                                                  const float* __restrict__ wt,
                                                  float* __restrict__ out) {
    __shared__ float patch[64][32];
    __shared__ int   cy0[32], cy1[32], cx0[32], cx1[32];
    __shared__ float cw0[32], cw1[32], cw2[32], cw3[32];

    int t   = threadIdx.x;
    int q   = blockIdx.x % 3;
    int row = blockIdx.x / 3;
    int ho  = row % 96;
    int b   = row / 96;
    int wo0 = q * 32;

    const float* xb = x + (size_t)b * CIN * HW;

    float acc[4][8];
#pragma unroll
    for (int j = 0; j < 4; j++)
#pragma unroll
        for (int p = 0; p < 8; p++) acc[j][p] = 0.f;

    int ocb = (t & 63) * 4;       // oc base (4 consecutive)
    int pb  = (t >> 6) * 8;       // pos base (8 consecutive)

    for (int k = 0; k < 9; k++) {
        int ky = k / 3, kx = k % 3;
        __syncthreads();
        if (t < 32) {
            int wo = wo0 + t;
            float dy = off[((size_t)b * 18 + 2 * k)     * HW + ho * WID + wo];
            float dx = off[((size_t)b * 18 + 2 * k + 1) * HW + ho * WID + wo];
            float sy = (float)(ho - 1 + ky) + dy;
            float sx = (float)(wo - 1 + kx) + dx;
            float y0f = floorf(sy), x0f = floorf(sx);
            float fy = sy - y0f, fx = sx - x0f;
            int y0 = (int)y0f, x0i = (int)x0f;
            int y1 = y0 + 1, x1 = x0i + 1;
            float vy0 = (y0  >= 0 && y0  < 96) ? 1.f : 0.f;
            float vy1 = (y1  >= 0 && y1  < 96) ? 1.f : 0.f;
            float vx0 = (x0i >= 0 && x0i < 96) ? 1.f : 0.f;
            float vx1 = (x1  >= 0 && x1  < 96) ? 1.f : 0.f;
            cy0[t] = min(max(y0, 0), 95) * WID;
            cy1[t] = min(max(y1, 0), 95) * WID;
            cx0[t] = min(max(x0i, 0), 95);
            cx1[t] = min(max(x1, 0), 95);
            cw0[t] = (1.f - fy) * (1.f - fx) * vy0 * vx0;
            cw1[t] = (1.f - fy) * fx         * vy0 * vx1;
            cw2[t] = fy         * (1.f - fx) * vy1 * vx0;
            cw3[t] = fy         * fx         * vy1 * vx1;
        }
        for (int cc = 0; cc < 4; cc++) {
            __syncthreads();
            // gather 64c x 32pos bilinear samples into LDS
#pragma unroll
            for (int i = 0; i < 8; i++) {
                int flat = i * 256 + t;
                int p  = flat & 31;
                int cl = flat >> 5;
                const float* xc = xb + (size_t)(cc * 64 + cl) * HW;
                float v = cw0[p] * xc[cy0[p] + cx0[p]] + cw1[p] * xc[cy0[p] + cx1[p]]
                        + cw2[p] * xc[cy1[p] + cx0[p]] + cw3[p] * xc[cy1[p] + cx1[p]];
                patch[cl][p] = v;
            }
            __syncthreads();
            const float* wp = wt + ((size_t)(k * 256 + cc * 64)) * 256 + ocb;
            for (int cl = 0; cl < 64; cl++) {
                float4 wv = *(const float4*)(wp + (size_t)cl * 256);
                float4 p0 = *(const float4*)&patch[cl][pb];
                float4 p1 = *(const float4*)&patch[cl][pb + 4];
                float wa[4] = {wv.x, wv.y, wv.z, wv.w};
                float pa[8] = {p0.x, p0.y, p0.z, p0.w, p1.x, p1.y, p1.z, p1.w};
#pragma unroll
                for (int j = 0; j < 4; j++)
#pragma unroll
                    for (int p = 0; p < 8; p++)
                        acc[j][p] += wa[j] * pa[p];
            }
        }
    }
    // epilogue: direct stores (no overlap between blocks)
#pragma unroll
    for (int j = 0; j < 4; j++) {
        float* ob = out + ((size_t)b * COUT + ocb + j) * HW + ho * WID + wo0 + pb;
        float4 o0 = make_float4(acc[j][0], acc[j][1], acc[j][2], acc[j][3]);
        float4 o1 = make_float4(acc[j][4], acc[j][5], acc[j][6], acc[j][7]);
        *(float4*)ob       = o0;
        *(float4*)(ob + 4) = o1;
    }
}

// One block per (b, group): reduce 8ch * 9216px = 73728 contiguous floats.
__global__ __launch_bounds__(256) void gn_stats(const float* __restrict__ out,
                                                float* __restrict__ stats) {
    __shared__ float sdata[512];
    int bg = blockIdx.x;
    const float4* b4 = (const float4*)(out + (size_t)bg * 73728);
    float s = 0.f, ss = 0.f;
    for (int i = threadIdx.x; i < 18432; i += 256) {
        float4 v = b4[i];
        s  += v.x + v.y + v.z + v.w;
        ss += v.x * v.x + v.y * v.y + v.z * v.z + v.w * v.w;
    }
    sdata[threadIdx.x] = s;
    sdata[256 + threadIdx.x] = ss;
    __syncthreads();
    for (int st = 128; st > 0; st >>= 1) {
        if (threadIdx.x < st) {
            sdata[threadIdx.x]       += sdata[threadIdx.x + st];
            sdata[256 + threadIdx.x] += sdata[256 + threadIdx.x + st];
        }
        __syncthreads();
    }
    if (threadIdx.x == 0) {
        float mean = sdata[0] / 73728.f;
        float var  = sdata[256] / 73728.f - mean * mean;
        stats[bg * 2]     = mean;
        stats[bg * 2 + 1] = rsqrtf(var + 1e-5f);
    }
}

__global__ __launch_bounds__(256) void gn_norm(float* __restrict__ out,
                                               const float* __restrict__ stats,
                                               const float* __restrict__ gamma,
                                               const float* __restrict__ beta) {
    int i4 = blockIdx.x * 256 + threadIdx.x;   // [0, 1179648)
    if (i4 >= 1179648) return;
    float4 v = ((const float4*)out)[i4];
    int e  = i4 * 4;
    int ch = (e / HW) & 255;
    int b  = e / (HW * 256);
    int bg = b * 32 + (ch >> 3);
    float mean = stats[bg * 2], rs = stats[bg * 2 + 1];
    float ga = gamma[ch] * rs;
    float be = beta[ch] - mean * ga;
    v.x = fmaxf(v.x * ga + be, 0.f);
    v.y = fmaxf(v.y * ga + be, 0.f);
    v.z = fmaxf(v.z * ga + be, 0.f);
    v.w = fmaxf(v.w * ga + be, 0.f);
    ((float4*)out)[i4] = v;
}

extern "C" void kernel_launch(void* const* d_in, const int* in_sizes, int n_in,
                              void* d_out, int out_size, void* d_ws, size_t ws_size,
                              hipStream_t stream) {
    const float* x        = (const float*)d_in[0];
    const float* offset_w = (const float*)d_in[1];
    const float* offset_b = (const float*)d_in[2];
    const float* conv_w   = (const float*)d_in[3];
    const float* gamma    = (const float*)d_in[4];
    const float* beta     = (const float*)d_in[5];
    float* out = (float*)d_out;
    float* ws  = (float*)d_ws;

    float* off   = ws;            // 331776 floats
    float* wt    = ws + 331776;   // 589824 floats
    float* stats = ws + 921600;   // 128 floats

    hipLaunchKernelGGL(init_off,    dim3(1296), dim3(256), 0, stream, off, offset_b);
    hipLaunchKernelGGL(transpose_w, dim3(2304), dim3(256), 0, stream, conv_w, wt);
    hipLaunchKernelGGL(offset_conv, dim3(576),  dim3(256), 0, stream, x, offset_w, off);
    hipLaunchKernelGGL(dconv_main,  dim3(576),  dim3(256), 0, stream, x, off, wt, out);
    hipLaunchKernelGGL(gn_stats,    dim3(64),   dim3(256), 0, stream, out, stats);
    hipLaunchKernelGGL(gn_norm,     dim3(4608), dim3(256), 0, stream, out, stats, gamma, beta);
}

// Round 2
// 323.103 us; speedup vs baseline: 1.9964x; 1.9964x over previous
//
#include <hip/hip_runtime.h>
#include <math.h>

#define HW 9216          // 96*96
#define WID 96
#define CIN 256
#define COUT 256
#define NTOT 18432       // B*HW
#define KC 2304          // CIN*9  (K of the implicit GEMM)

typedef short bf16x8 __attribute__((ext_vector_type(8)));
typedef float f32x4  __attribute__((ext_vector_type(4)));

__device__ __forceinline__ unsigned short f2bf(float f) {
    union { float f; unsigned int u; } v; v.f = f;
    unsigned int u = v.u;
    return (unsigned short)((u + 0x7fffu + ((u >> 16) & 1u)) >> 16);  // RNE
}

// ws layout (float offsets):
//   off      : 0        .. 331776
//   stats    : 331776   .. 331904   (64 * {sum, sumsq}, atomically accumulated)
//   wb bf16  : 331904   .. 626816   (256 x 2304 ushort: wb[oc][k*256+c])
//   meta_idx : 626816   .. 1290368  (9*18432 int4)
//   meta_w   : 1290368  .. 1953920  (9*18432 float4)
//   P bf16   : 1953920  ..          (Nc x 2304 ushort, chunked)

__global__ __launch_bounds__(256) void init_ws(float* __restrict__ off,
                                               const float* __restrict__ offset_b,
                                               float* __restrict__ stats) {
    int i = blockIdx.x * 256 + threadIdx.x;
    if (i < 331776) {
        int ch = (i / HW) % 18;
        off[i] = offset_b[ch];
    }
    if (i < 128) stats[i] = 0.f;
}

// 3x3 pad-1 conv -> 18 offset channels. 16 c-chunks x 72 = 1152 blocks.
__global__ __launch_bounds__(256) void offset_conv(const float* __restrict__ x,
                                                   const float* __restrict__ ow,
                                                   float* __restrict__ off) {
    int chunk = blockIdx.x / 72;
    int pg = (blockIdx.x % 72) * 256 + threadIdx.x;
    int b  = pg / HW;
    int p  = pg % HW;
    int ho = p / WID, wo = p % WID;
    const float* xb = x + (size_t)b * CIN * HW;

    float acc[18];
#pragma unroll
    for (int ch = 0; ch < 18; ch++) acc[ch] = 0.f;

    int c0 = chunk * 16;
    for (int ci = 0; ci < 16; ci++) {
        int c = c0 + ci;
        const float* xc = xb + (size_t)c * HW;
#pragma unroll
        for (int ky = 0; ky < 3; ky++) {
            int y = ho - 1 + ky;
            if (y < 0 || y >= 96) continue;
#pragma unroll
            for (int kx = 0; kx < 3; kx++) {
                int xx = wo - 1 + kx;
                float xv = (xx >= 0 && xx < 96) ? xc[y * WID + xx] : 0.f;
                int widx = c * 9 + ky * 3 + kx;
#pragma unroll
                for (int ch = 0; ch < 18; ch++)
                    acc[ch] += xv * ow[ch * (CIN * 9) + widx];
            }
        }
    }
#pragma unroll
    for (int ch = 0; ch < 18; ch++)
        atomicAdd(&off[((size_t)b * 18 + ch) * HW + p], acc[ch]);
}

// conv_w [oc][c][k] -> wb bf16 [oc][k*256+c]
__global__ __launch_bounds__(256) void transpose_wb(const float* __restrict__ cw,
                                                    unsigned short* __restrict__ wb) {
    int i = blockIdx.x * 256 + threadIdx.x;   // [0, 589824)
    if (i >= 589824) return;
    int oc = i / KC;
    int kc = i % KC;
    int k  = kc >> 8;
    int c  = kc & 255;
    wb[i] = f2bf(cw[(oc * CIN + c) * 9 + k]);
}

// per (k, n): 4 clamped plane-local corner indices + 4 bilinear weights
__global__ __launch_bounds__(256) void compute_meta(const float* __restrict__ off,
                                                    int* __restrict__ midx,
                                                    float* __restrict__ mw) {
    int g = blockIdx.x * 256 + threadIdx.x;
    if (g >= 9 * NTOT) return;
    int k = g / NTOT;
    int n = g % NTOT;
    int b = n / HW, p = n % HW;
    int ho = p / WID, wo = p % WID;
    int ky = k / 3, kx = k % 3;
    float dy = off[((size_t)b * 18 + 2 * k)     * HW + p];
    float dx = off[((size_t)b * 18 + 2 * k + 1) * HW + p];
    float sy = (float)(ho - 1 + ky) + dy;
    float sx = (float)(wo - 1 + kx) + dx;
    float y0f = floorf(sy), x0f = floorf(sx);
    float fy = sy - y0f, fx = sx - x0f;
    int y0 = (int)y0f, x0 = (int)x0f;
    int y1 = y0 + 1, x1 = x0 + 1;
    float vy0 = (y0 >= 0 && y0 < 96) ? 1.f : 0.f;
    float vy1 = (y1 >= 0 && y1 < 96) ? 1.f : 0.f;
    float vx0 = (x0 >= 0 && x0 < 96) ? 1.f : 0.f;
    float vx1 = (x1 >= 0 && x1 < 96) ? 1.f : 0.f;
    int cy0 = min(max(y0, 0), 95) * WID, cy1 = min(max(y1, 0), 95) * WID;
    int cx0 = min(max(x0, 0), 95),       cx1 = min(max(x1, 0), 95);
    ((int4*)midx)[g]  = make_int4(cy0 + cx0, cy0 + cx1, cy1 + cx0, cy1 + cx1);
    ((float4*)mw)[g]  = make_float4((1.f - fy) * (1.f - fx) * vy0 * vx0,
                                    (1.f - fy) * fx         * vy0 * vx1,
                                    fy         * (1.f - fx) * vy1 * vx0,
                                    fy         * fx         * vy1 * vx1);
}

// Bilinear gather -> P[n_local][k*256+c] bf16.
// Grid: (Nc/64, 8 c-tiles, 9 k). Phase 1: n-contiguous lanes (coalesced x reads),
// LDS [32c][66] transpose. Phase 2: kc-contiguous 16B writes.
__global__ __launch_bounds__(256) void gather_patches(const float* __restrict__ x,
                                                      const int* __restrict__ midx,
                                                      const float* __restrict__ mw,
                                                      unsigned short* __restrict__ P,
                                                      int n0) {
    __shared__ unsigned short L[32 * 66];
    int t  = threadIdx.x;
    int k  = blockIdx.z;
    int ct = blockIdx.y;
    int nt = blockIdx.x;
    int nl = nt * 64 + (t & 63);
    int n  = n0 + nl;
    int b  = n / HW;
    int4   I = ((const int4*)midx)[k * NTOT + n];
    float4 W = ((const float4*)mw)[k * NTOT + n];
    const float* xb = x + (size_t)b * CIN * HW;
    int cl0 = t >> 6;
#pragma unroll
    for (int i = 0; i < 8; i++) {
        int cl = cl0 + i * 4;
        const float* xc = xb + (size_t)(ct * 32 + cl) * HW;
        float v = W.x * xc[I.x] + W.y * xc[I.y] + W.z * xc[I.z] + W.w * xc[I.w];
        L[cl * 66 + (t & 63)] = f2bf(v);
    }
    __syncthreads();
    int row = t >> 2;   // n' within tile
    int q   = t & 3;    // 8-c group
    unsigned short tmp[8] __attribute__((aligned(16)));
#pragma unroll
    for (int j = 0; j < 8; j++) tmp[j] = L[(q * 8 + j) * 66 + row];
    size_t dst = (size_t)(nt * 64 + row) * KC + k * 256 + ct * 32 + q * 8;
    *((int4*)(P + dst)) = *((const int4*)tmp);
}

// bf16 MFMA GEMM: C[256][Nc] += wb[256][2304] x P^T. Block tile 64M x 128N,
// 4 waves each 64M x 32N (4x2 16x16 tiles). Reg-prefetch double buffer.
__global__ __launch_bounds__(256) void gemm_mfma(const unsigned short* __restrict__ wb,
                                                 const unsigned short* __restrict__ P,
                                                 float* __restrict__ out, int n0) {
    __shared__ __align__(16) unsigned short As[64 * 40];
    __shared__ __align__(16) unsigned short Bs[128 * 40];
    int t    = threadIdx.x;
    int m0   = blockIdx.y * 64;
    int nb   = blockIdx.x;
    int wave = t >> 6;
    int lane = t & 63;
    int l15  = lane & 15, quad = lane >> 4;

    f32x4 acc[4][2];
#pragma unroll
    for (int i = 0; i < 4; i++)
#pragma unroll
        for (int j = 0; j < 2; j++) acc[i][j] = (f32x4)0.f;

    const unsigned short* Ap  = wb + (size_t)(m0 + (t >> 2)) * KC + (t & 3) * 8;
    const unsigned short* Bp0 = P  + ((size_t)nb * 128 + (t >> 2)) * KC + (t & 3) * 8;
    const unsigned short* Bp1 = Bp0 + (size_t)64 * KC;
    int wr = (t >> 2) * 40 + (t & 3) * 8;

    int4 ra  = *(const int4*)Ap;
    int4 rb0 = *(const int4*)Bp0;
    int4 rb1 = *(const int4*)Bp1;

    for (int kc = 0; kc < KC; kc += 32) {
        __syncthreads();
        *(int4*)&As[wr]           = ra;
        *(int4*)&Bs[wr]           = rb0;
        *(int4*)&Bs[wr + 64 * 40] = rb1;
        __syncthreads();
        if (kc + 32 < KC) {
            ra  = *(const int4*)(Ap  + kc + 32);
            rb0 = *(const int4*)(Bp0 + kc + 32);
            rb1 = *(const int4*)(Bp1 + kc + 32);
        }
        bf16x8 a[4], b[2];
#pragma unroll
        for (int i = 0; i < 4; i++)
            a[i] = *(const bf16x8*)&As[(i * 16 + l15) * 40 + quad * 8];
#pragma unroll
        for (int j = 0; j < 2; j++)
            b[j] = *(const bf16x8*)&Bs[(wave * 32 + j * 16 + l15) * 40 + quad * 8];
#pragma unroll
        for (int i = 0; i < 4; i++)
#pragma unroll
            for (int j = 0; j < 2; j++)
                acc[i][j] = __builtin_amdgcn_mfma_f32_16x16x32_bf16(a[i], b[j], acc[i][j], 0, 0, 0);
    }

    int nbase = n0 + nb * 128 + wave * 32;
#pragma unroll
    for (int i = 0; i < 4; i++) {
#pragma unroll
        for (int j = 0; j < 2; j++) {
            int n  = nbase + j * 16 + l15;
            int b_ = n / HW, p = n % HW;
            int m  = m0 + i * 16 + quad * 4;
            float* ob = out + (size_t)b_ * COUT * HW + (size_t)m * HW + p;
#pragma unroll
            for (int r = 0; r < 4; r++) ob[(size_t)r * HW] = acc[i][j][r];
        }
    }
}

// Partial GN stats: 512 blocks, each reduces 9216 floats, atomics into stats.
__global__ __launch_bounds__(256) void gn_stats(const float* __restrict__ out,
                                                float* __restrict__ stats) {
    __shared__ float sdata[512];
    int blk = blockIdx.x;          // [0,512)
    int bg  = blk >> 3;
    const float4* b4 = (const float4*)(out + (size_t)bg * 73728 + (size_t)(blk & 7) * 9216);
    float s = 0.f, ss = 0.f;
    for (int i = threadIdx.x; i < 2304; i += 256) {
        float4 v = b4[i];
        s  += v.x + v.y + v.z + v.w;
        ss += v.x * v.x + v.y * v.y + v.z * v.z + v.w * v.w;
    }
    sdata[threadIdx.x]       = s;
    sdata[256 + threadIdx.x] = ss;
    __syncthreads();
    for (int st = 128; st > 0; st >>= 1) {
        if (threadIdx.x < st) {
            sdata[threadIdx.x]       += sdata[threadIdx.x + st];
            sdata[256 + threadIdx.x] += sdata[256 + threadIdx.x + st];
        }
        __syncthreads();
    }
    if (threadIdx.x == 0) {
        atomicAdd(&stats[bg * 2],     sdata[0]);
        atomicAdd(&stats[bg * 2 + 1], sdata[256]);
    }
}

__global__ __launch_bounds__(256) void gn_norm(float* __restrict__ out,
                                               const float* __restrict__ stats,
                                               const float* __restrict__ gamma,
                                               const float* __restrict__ beta) {
    int i4 = blockIdx.x * 256 + threadIdx.x;   // [0, 1179648)
    if (i4 >= 1179648) return;
    float4 v = ((const float4*)out)[i4];
    int e  = i4 * 4;
    int ch = (e / HW) & 255;
    int b  = e / (HW * 256);
    int bg = b * 32 + (ch >> 3);
    float s = stats[bg * 2], ss = stats[bg * 2 + 1];
    float mean = s * (1.f / 73728.f);
    float rs   = rsqrtf(ss * (1.f / 73728.f) - mean * mean + 1e-5f);
    float ga = gamma[ch] * rs;
    float be = beta[ch] - mean * ga;
    v.x = fmaxf(v.x * ga + be, 0.f);
    v.y = fmaxf(v.y * ga + be, 0.f);
    v.z = fmaxf(v.z * ga + be, 0.f);
    v.w = fmaxf(v.w * ga + be, 0.f);
    ((float4*)out)[i4] = v;
}

extern "C" void kernel_launch(void* const* d_in, const int* in_sizes, int n_in,
                              void* d_out, int out_size, void* d_ws, size_t ws_size,
                              hipStream_t stream) {
    const float* x        = (const float*)d_in[0];
    const float* offset_w = (const float*)d_in[1];
    const float* offset_b = (const float*)d_in[2];
    const float* conv_w   = (const float*)d_in[3];
    const float* gamma    = (const float*)d_in[4];
    const float* beta     = (const float*)d_in[5];
    float* out = (float*)d_out;
    float* ws  = (float*)d_ws;

    float*          off   = ws;
    float*          stats = ws + 331776;
    unsigned short* wb    = (unsigned short*)(ws + 331904);
    int*            midx  = (int*)(ws + 626816);
    float*          mw    = ws + 1290368;
    unsigned short* P     = (unsigned short*)(ws + 1953920);

    const size_t baseB = 1953920ull * 4ull;
    int Nc;
    if      (ws_size >= baseB + (size_t)18432 * KC * 2) Nc = 18432;
    else if (ws_size >= baseB + (size_t)9216  * KC * 2) Nc = 9216;
    else if (ws_size >= baseB + (size_t)4608  * KC * 2) Nc = 4608;
    else if (ws_size >= baseB + (size_t)2304  * KC * 2) Nc = 2304;
    else                                                Nc = 1152;

    hipLaunchKernelGGL(init_ws,      dim3(1296), dim3(256), 0, stream, off, offset_b, stats);
    hipLaunchKernelGGL(offset_conv,  dim3(1152), dim3(256), 0, stream, x, offset_w, off);
    hipLaunchKernelGGL(transpose_wb, dim3(2304), dim3(256), 0, stream, conv_w, wb);
    hipLaunchKernelGGL(compute_meta, dim3(648),  dim3(256), 0, stream, off, midx, mw);
    for (int n0 = 0; n0 < NTOT; n0 += Nc) {
        hipLaunchKernelGGL(gather_patches, dim3(Nc / 64, 8, 9), dim3(256), 0, stream,
                           x, midx, mw, P, n0);
        hipLaunchKernelGGL(gemm_mfma, dim3(Nc / 128, 4), dim3(256), 0, stream,
                           wb, P, out, n0);
    }
    hipLaunchKernelGGL(gn_stats, dim3(512),  dim3(256), 0, stream, out, stats);
    hipLaunchKernelGGL(gn_norm,  dim3(4608), dim3(256), 0, stream, out, stats, gamma, beta);
}

// Round 3
// 253.982 us; speedup vs baseline: 2.5397x; 1.2721x over previous
//
#include <hip/hip_runtime.h>
#include <math.h>

#define HW 9216          // 96*96
#define WID 96
#define CIN 256
#define COUT 256
#define NTOT 18432       // B*HW
#define KC 2304          // CIN*9  (K of the implicit GEMM)

typedef short bf16x8 __attribute__((ext_vector_type(8)));
typedef float f32x4  __attribute__((ext_vector_type(4)));

__device__ __forceinline__ unsigned short f2bf(float f) {
    union { float f; unsigned int u; } v; v.f = f;
    unsigned int u = v.u;
    return (unsigned short)((u + 0x7fffu + ((u >> 16) & 1u)) >> 16);  // RNE
}

// ws layout (float offsets):
//   off      : 0        .. 331776
//   stats    : 331776   .. 331904   (64 * {sum, sumsq}, atomic-accumulated)
//   wb bf16  : 331904   .. 626816   (256 x 2304 ushort: wb[oc][k*256+c])
//   meta_idx : 626816   .. 1290368  (9*18432 int4, plane-local corner idx)
//   meta_w   : 1290368  .. 1953920  (9*18432 float4 bilinear weights)
//   x_t      : 1953920  .. 6672512  (NHWC: [b][p][c] fp32)
//   P bf16   : 6672512  ..          (Nc x 2304 ushort, chunked)

__global__ __launch_bounds__(256) void init_ws(float* __restrict__ off,
                                               const float* __restrict__ offset_b,
                                               float* __restrict__ stats) {
    int i = blockIdx.x * 256 + threadIdx.x;
    if (i < 331776) {
        int ch = (i / HW) % 18;
        off[i] = offset_b[ch];
    }
    if (i < 128) stats[i] = 0.f;
}

// 3x3 pad-1 conv -> 18 offset channels. 16 c-chunks x 72 = 1152 blocks.
__global__ __launch_bounds__(256) void offset_conv(const float* __restrict__ x,
                                                   const float* __restrict__ ow,
                                                   float* __restrict__ off) {
    int chunk = blockIdx.x / 72;
    int pg = (blockIdx.x % 72) * 256 + threadIdx.x;
    int b  = pg / HW;
    int p  = pg % HW;
    int ho = p / WID, wo = p % WID;
    const float* xb = x + (size_t)b * CIN * HW;

    float acc[18];
#pragma unroll
    for (int ch = 0; ch < 18; ch++) acc[ch] = 0.f;

    int c0 = chunk * 16;
    for (int ci = 0; ci < 16; ci++) {
        int c = c0 + ci;
        const float* xc = xb + (size_t)c * HW;
#pragma unroll
        for (int ky = 0; ky < 3; ky++) {
            int y = ho - 1 + ky;
            if (y < 0 || y >= 96) continue;
#pragma unroll
            for (int kx = 0; kx < 3; kx++) {
                int xx = wo - 1 + kx;
                float xv = (xx >= 0 && xx < 96) ? xc[y * WID + xx] : 0.f;
                int widx = c * 9 + ky * 3 + kx;
#pragma unroll
                for (int ch = 0; ch < 18; ch++)
                    acc[ch] += xv * ow[ch * (CIN * 9) + widx];
            }
        }
    }
#pragma unroll
    for (int ch = 0; ch < 18; ch++)
        atomicAdd(&off[((size_t)b * 18 + ch) * HW + p], acc[ch]);
}

// conv_w [oc][c][k] -> wb bf16 [oc][k*256+c]
__global__ __launch_bounds__(256) void transpose_wb(const float* __restrict__ cw,
                                                    unsigned short* __restrict__ wb) {
    int i = blockIdx.x * 256 + threadIdx.x;   // [0, 589824)
    if (i >= 589824) return;
    int oc = i / KC;
    int kc = i % KC;
    int k  = kc >> 8;
    int c  = kc & 255;
    wb[i] = f2bf(cw[(oc * CIN + c) * 9 + k]);
}

// x NCHW -> x_t NHWC. Grid: (288 p-tiles, 8 c-tiles, 2 b), 32x32 LDS tile.
__global__ __launch_bounds__(256) void transpose_x(const float* __restrict__ x,
                                                   float* __restrict__ xt) {
    __shared__ float L[32][33];
    int t  = threadIdx.x;
    int pt = blockIdx.x, ct = blockIdx.y, b = blockIdx.z;
    int pl = t & 31;
    int ch = t >> 5;       // 0..7
#pragma unroll
    for (int i = 0; i < 4; i++) {
        int cl = ch * 4 + i;
        L[cl][pl] = x[((size_t)(b * CIN + ct * 32 + cl)) * HW + pt * 32 + pl];
    }
    __syncthreads();
    int cc = t & 31;
#pragma unroll
    for (int i = 0; i < 4; i++) {
        int pr = ch * 4 + i;
        xt[((size_t)(b * HW + pt * 32 + pr)) * 256 + ct * 32 + cc] = L[cc][pr];
    }
}

// per (k, n): 4 clamped plane-local corner indices + 4 bilinear weights
__global__ __launch_bounds__(256) void compute_meta(const float* __restrict__ off,
                                                    int* __restrict__ midx,
                                                    float* __restrict__ mw) {
    int g = blockIdx.x * 256 + threadIdx.x;
    if (g >= 9 * NTOT) return;
    int k = g / NTOT;
    int n = g % NTOT;
    int b = n / HW, p = n % HW;
    int ho = p / WID, wo = p % WID;
    int ky = k / 3, kx = k % 3;
    float dy = off[((size_t)b * 18 + 2 * k)     * HW + p];
    float dx = off[((size_t)b * 18 + 2 * k + 1) * HW + p];
    float sy = (float)(ho - 1 + ky) + dy;
    float sx = (float)(wo - 1 + kx) + dx;
    float y0f = floorf(sy), x0f = floorf(sx);
    float fy = sy - y0f, fx = sx - x0f;
    int y0 = (int)y0f, x0 = (int)x0f;
    int y1 = y0 + 1, x1 = x0 + 1;
    float vy0 = (y0 >= 0 && y0 < 96) ? 1.f : 0.f;
    float vy1 = (y1 >= 0 && y1 < 96) ? 1.f : 0.f;
    float vx0 = (x0 >= 0 && x0 < 96) ? 1.f : 0.f;
    float vx1 = (x1 >= 0 && x1 < 96) ? 1.f : 0.f;
    int cy0 = min(max(y0, 0), 95) * WID, cy1 = min(max(y1, 0), 95) * WID;
    int cx0 = min(max(x0, 0), 95),       cx1 = min(max(x1, 0), 95);
    ((int4*)midx)[g]  = make_int4(cy0 + cx0, cy0 + cx1, cy1 + cx0, cy1 + cx1);
    ((float4*)mw)[g]  = make_float4((1.f - fy) * (1.f - fx) * vy0 * vx0,
                                    (1.f - fy) * fx         * vy0 * vx1,
                                    fy         * (1.f - fx) * vy1 * vx0,
                                    fy         * fx         * vy1 * vx1);
}

// Gather v2: one wave per (n,k). 4 coalesced 1KB corner-row reads (NHWC),
// lane handles 4 channels. Grid: (9 k, Nc/4) — k fastest for window locality.
__global__ __launch_bounds__(256) void gather2(const float* __restrict__ xt,
                                               const int* __restrict__ midx,
                                               const float* __restrict__ mw,
                                               unsigned short* __restrict__ P,
                                               int n0) {
    int t    = threadIdx.x;
    int k    = blockIdx.x;          // 0..8
    int wave = t >> 6;
    int lane = t & 63;
    int nl   = blockIdx.y * 4 + wave;
    int n    = n0 + nl;
    int4   I = ((const int4*)midx)[k * NTOT + n];
    float4 W = ((const float4*)mw)[k * NTOT + n];
    const float* xb = xt + (size_t)(n / HW) * (HW * 256);
    int c4 = lane * 4;
    float4 v0 = *(const float4*)(xb + (size_t)I.x * 256 + c4);
    float4 v1 = *(const float4*)(xb + (size_t)I.y * 256 + c4);
    float4 v2 = *(const float4*)(xb + (size_t)I.z * 256 + c4);
    float4 v3 = *(const float4*)(xb + (size_t)I.w * 256 + c4);
    float r0 = W.x * v0.x + W.y * v1.x + W.z * v2.x + W.w * v3.x;
    float r1 = W.x * v0.y + W.y * v1.y + W.z * v2.y + W.w * v3.y;
    float r2 = W.x * v0.z + W.y * v1.z + W.z * v2.z + W.w * v3.z;
    float r3 = W.x * v0.w + W.y * v1.w + W.z * v2.w + W.w * v3.w;
    uint2 o;
    o.x = (unsigned)f2bf(r0) | ((unsigned)f2bf(r1) << 16);
    o.y = (unsigned)f2bf(r2) | ((unsigned)f2bf(r3) << 16);
    *((uint2*)(P + (size_t)nl * KC + k * 256 + c4)) = o;
}

// bf16 MFMA GEMM: C[256][Nc] += wb[256][2304] x P^T. Block tile 64M x 128N.
// Grid: (4 m-blocks FASTEST, Nc/128) -> consecutive blocks share the B-tile in L2.
// Fused GroupNorm partial stats (sum, sumsq) via LDS + global atomics.
__global__ __launch_bounds__(256) void gemm_mfma(const unsigned short* __restrict__ wb,
                                                 const unsigned short* __restrict__ P,
                                                 float* __restrict__ out,
                                                 float* __restrict__ stats, int n0) {
    __shared__ __align__(16) unsigned short As[64 * 40];
    __shared__ __align__(16) unsigned short Bs[128 * 40];
    __shared__ float sgrp[16];
    int t    = threadIdx.x;
    int m0   = blockIdx.x * 64;     // m fastest
    int nb   = blockIdx.y;
    int wave = t >> 6;
    int lane = t & 63;
    int l15  = lane & 15, quad = lane >> 4;

    f32x4 acc[4][2];
#pragma unroll
    for (int i = 0; i < 4; i++)
#pragma unroll
        for (int j = 0; j < 2; j++) acc[i][j] = (f32x4)0.f;

    const unsigned short* Ap  = wb + (size_t)(m0 + (t >> 2)) * KC + (t & 3) * 8;
    const unsigned short* Bp0 = P  + ((size_t)nb * 128 + (t >> 2)) * KC + (t & 3) * 8;
    const unsigned short* Bp1 = Bp0 + (size_t)64 * KC;
    int wr = (t >> 2) * 40 + (t & 3) * 8;

    int4 ra  = *(const int4*)Ap;
    int4 rb0 = *(const int4*)Bp0;
    int4 rb1 = *(const int4*)Bp1;

    for (int kc = 0; kc < KC; kc += 32) {
        __syncthreads();
        *(int4*)&As[wr]           = ra;
        *(int4*)&Bs[wr]           = rb0;
        *(int4*)&Bs[wr + 64 * 40] = rb1;
        __syncthreads();
        if (kc + 32 < KC) {
            ra  = *(const int4*)(Ap  + kc + 32);
            rb0 = *(const int4*)(Bp0 + kc + 32);
            rb1 = *(const int4*)(Bp1 + kc + 32);
        }
        bf16x8 a[4], b[2];
#pragma unroll
        for (int i = 0; i < 4; i++)
            a[i] = *(const bf16x8*)&As[(i * 16 + l15) * 40 + quad * 8];
#pragma unroll
        for (int j = 0; j < 2; j++)
            b[j] = *(const bf16x8*)&Bs[(wave * 32 + j * 16 + l15) * 40 + quad * 8];
#pragma unroll
        for (int i = 0; i < 4; i++)
#pragma unroll
            for (int j = 0; j < 2; j++)
                acc[i][j] = __builtin_amdgcn_mfma_f32_16x16x32_bf16(a[i], b[j], acc[i][j], 0, 0, 0);
    }

    if (t < 16) sgrp[t] = 0.f;
    __syncthreads();

    int nbase = n0 + nb * 128 + wave * 32;
    int qh = quad >> 1;
    float s_l[4]  = {0.f, 0.f, 0.f, 0.f};
    float ss_l[4] = {0.f, 0.f, 0.f, 0.f};
#pragma unroll
    for (int i = 0; i < 4; i++) {
#pragma unroll
        for (int j = 0; j < 2; j++) {
            int n  = nbase + j * 16 + l15;
            int b_ = n / HW, p = n % HW;
            int m  = m0 + i * 16 + quad * 4;
            float* ob = out + (size_t)b_ * COUT * HW + (size_t)m * HW + p;
#pragma unroll
            for (int r = 0; r < 4; r++) {
                float v = acc[i][j][r];
                ob[(size_t)r * HW] = v;
                s_l[i]  += v;
                ss_l[i] += v * v;
            }
        }
    }
#pragma unroll
    for (int i = 0; i < 4; i++) {
        int g = i * 2 + qh;
        atomicAdd(&sgrp[g],     s_l[i]);
        atomicAdd(&sgrp[8 + g], ss_l[i]);
    }
    __syncthreads();
    if (t < 16) {
        int b_ = (n0 + nb * 128) / HW;
        int gg = b_ * 32 + (m0 >> 3) + (t & 7);
        atomicAdd(&stats[gg * 2 + (t >> 3)], sgrp[(t >> 3) * 8 + (t & 7)]);
    }
}

__global__ __launch_bounds__(256) void gn_norm(float* __restrict__ out,
                                               const float* __restrict__ stats,
                                               const float* __restrict__ gamma,
                                               const float* __restrict__ beta) {
    int i4 = blockIdx.x * 256 + threadIdx.x;   // [0, 1179648)
    if (i4 >= 1179648) return;
    float4 v = ((const float4*)out)[i4];
    int e  = i4 * 4;
    int ch = (e / HW) & 255;
    int b  = e / (HW * 256);
    int bg = b * 32 + (ch >> 3);
    float s = stats[bg * 2], ss = stats[bg * 2 + 1];
    float mean = s * (1.f / 73728.f);
    float rs   = rsqrtf(ss * (1.f / 73728.f) - mean * mean + 1e-5f);
    float ga = gamma[ch] * rs;
    float be = beta[ch] - mean * ga;
    v.x = fmaxf(v.x * ga + be, 0.f);
    v.y = fmaxf(v.y * ga + be, 0.f);
    v.z = fmaxf(v.z * ga + be, 0.f);
    v.w = fmaxf(v.w * ga + be, 0.f);
    ((float4*)out)[i4] = v;
}

extern "C" void kernel_launch(void* const* d_in, const int* in_sizes, int n_in,
                              void* d_out, int out_size, void* d_ws, size_t ws_size,
                              hipStream_t stream) {
    const float* x        = (const float*)d_in[0];
    const float* offset_w = (const float*)d_in[1];
    const float* offset_b = (const float*)d_in[2];
    const float* conv_w   = (const float*)d_in[3];
    const float* gamma    = (const float*)d_in[4];
    const float* beta     = (const float*)d_in[5];
    float* out = (float*)d_out;
    float* ws  = (float*)d_ws;

    float*          off   = ws;
    float*          stats = ws + 331776;
    unsigned short* wb    = (unsigned short*)(ws + 331904);
    int*            midx  = (int*)(ws + 626816);
    float*          mw    = ws + 1290368;
    float*          xt    = ws + 1953920;
    unsigned short* P     = (unsigned short*)(ws + 6672512);

    const size_t baseB = 6672512ull * 4ull;
    int Nc;
    if      (ws_size >= baseB + (size_t)18432 * KC * 2) Nc = 18432;
    else if (ws_size >= baseB + (size_t)9216  * KC * 2) Nc = 9216;
    else if (ws_size >= baseB + (size_t)4608  * KC * 2) Nc = 4608;
    else                                                Nc = 2304;

    hipLaunchKernelGGL(init_ws,      dim3(1296), dim3(256), 0, stream, off, offset_b, stats);
    hipLaunchKernelGGL(offset_conv,  dim3(1152), dim3(256), 0, stream, x, offset_w, off);
    hipLaunchKernelGGL(transpose_wb, dim3(2304), dim3(256), 0, stream, conv_w, wb);
    hipLaunchKernelGGL(transpose_x,  dim3(288, 8, 2), dim3(256), 0, stream, x, xt);
    hipLaunchKernelGGL(compute_meta, dim3(648),  dim3(256), 0, stream, off, midx, mw);
    for (int n0 = 0; n0 < NTOT; n0 += Nc) {
        hipLaunchKernelGGL(gather2, dim3(9, Nc / 4), dim3(256), 0, stream,
                           xt, midx, mw, P, n0);
        hipLaunchKernelGGL(gemm_mfma, dim3(4, Nc / 128), dim3(256), 0, stream,
                           wb, P, out, stats, n0);
    }
    hipLaunchKernelGGL(gn_norm, dim3(4608), dim3(256), 0, stream, out, stats, gamma, beta);
}